// Round 2
// baseline (1346.584 us; speedup 1.0000x reference)
//
#include <hip/hip_runtime.h>
#include <math.h>

#define NLEV 24
#define CAPM 262144
#define HID 32

// ws layout: [0..23] = 1/scale (fp32-rounded like reference), [24..47] = c2f window,
//            [48] = number of active levels (prefix with window > 0)
__global__ void init_consts(const int* __restrict__ iter_p, float* __restrict__ ws) {
    __shared__ float wloc[NLEV];
    int l = threadIdx.x;
    if (l < NLEV) {
        double scale;
        if (l == 0) scale = 1.0;
        else if (l == NLEV - 1) scale = 0.0001;
        else scale = pow(10.0, -((double)(4 * l)) / 23.0);
        float scale_f = (float)scale;                 // reference casts geomspace to fp32
        ws[l] = (float)(1.0 / (double)scale_f);       // correctly-rounded fp32 reciprocal
        float t = (float)iter_p[0] / 10000.0f;
        t = fminf(fmaxf(t, 0.0f), 1.0f);
        float alpha = (0.3f + 0.7f * t) * 24.0f;
        float x = fminf(fmaxf(alpha - (float)l, 0.0f), 1.0f);
        float win = 0.5f * (1.0f - (float)cos(M_PI * (double)x));
        ws[NLEV + l] = win;
        wloc[l] = win;
    }
    __syncthreads();
    if (l == 0) {
        int cnt = 0;
        for (int i = 0; i < NLEV; i++) cnt += (wloc[i] > 0.0f) ? 1 : 0;
        ws[2 * NLEV] = (float)cnt;
    }
}

// Exact-erf gelu with fast path. Activations here are ~1e-3, so the |z|<0.5
// Taylor path (abs err < 1e-6 in erf -> ~2e-7 in gelu, budget 2e-4) is taken
// by all lanes; erff fallback kept for robustness (wave-uniform, never hit).
__device__ __forceinline__ float gelu_fast(float x) {
    float z = 0.70710678118654752f * x;
    float z2 = z * z;
    float er;
    if (__builtin_expect(z2 < 0.25f, 1)) {
        const float c0 = 1.1283791670955126f;     // 2/sqrt(pi)
        const float c1 = -0.37612638903183752f;   // -c0/3
        const float c2 = 0.11283791670955126f;    // c0/10
        const float c3 = -0.026866170645131251f;  // -c0/42
        const float c4 = 0.0052239776254421878f;  // c0/216
        float p = fmaf(z2, c4, c3);
        p = fmaf(z2, p, c2);
        p = fmaf(z2, p, c1);
        p = fmaf(z2, p, c0);
        er = z * p;
    } else {
        er = erff(z);
    }
    return 0.5f * x * (1.0f + er);
}

// Permutohedral lattice setup for one level: barycentric weights + 4 hash indices.
// Arithmetic identical to the round-1 verified version.
__device__ __forceinline__ void level_setup(
    float px, float py, float pz,
    const float* __restrict__ shifts, const float* __restrict__ cons, int l,
    float& wg0, float& wg1, float& wg2, float& wg3, float& win,
    unsigned& hA, unsigned& hB, unsigned& hC, unsigned& hD)
{
    const float SF0 = 2.3094010767585034f;  // 4/sqrt(3)
    const float SF1 = 1.3333333333333333f;  // 4/3
    const float SF2 = 0.9428090415820634f;  // 2*sqrt(2)/3

    win = cons[NLEV + l];
    float inv = cons[l];
    float p0 = fmaf(px, inv, shifts[3 * l + 0]);
    float p1 = fmaf(py, inv, shifts[3 * l + 1]);
    float p2 = fmaf(pz, inv, shifts[3 * l + 2]);
    float c0 = p0 * SF0, c1 = p1 * SF1, c2 = p2 * SF2;
    float s1 = c1 + c2;
    float s0 = c0 + s1;
    float e0 = s0;
    float e1 = s1 - c0;
    float e2 = c2 - 2.0f * c1;
    float e3 = -3.0f * c2;
    float r0f = rintf(e0 * 0.25f) * 4.0f;
    float r1f = rintf(e1 * 0.25f) * 4.0f;
    float r2f = rintf(e2 * 0.25f) * 4.0f;
    float r3f = rintf(e3 * 0.25f) * 4.0f;
    int sum_ = (int)rintf((r0f + r1f + r2f + r3f) * 0.25f);
    float d0 = e0 - r0f, d1 = e1 - r1f, d2 = e2 - r2f, d3 = e3 - r3f;
    // rank = position in stable descending argsort of diff
    int k0 = (int)(d1 > d0) + (int)(d2 > d0) + (int)(d3 > d0) + sum_;
    int k1 = (int)(d0 > d1) + (int)(d2 > d1) + (int)(d3 > d1)
           + (int)(d0 == d1) + sum_;
    int k2 = (int)(d0 > d2) + (int)(d1 > d2) + (int)(d3 > d2)
           + (int)(d0 == d2) + (int)(d1 == d2) + sum_;
    int k3 = (int)(d0 > d3) + (int)(d1 > d3) + (int)(d2 > d3)
           + (int)(d0 == d3) + (int)(d1 == d3) + (int)(d2 == d3) + sum_;
    int a0 = (k0 < 0) ? 4 : ((k0 > 3) ? -4 : 0); k0 += a0; r0f += (float)a0;
    int a1 = (k1 < 0) ? 4 : ((k1 > 3) ? -4 : 0); k1 += a1; r1f += (float)a1;
    int a2 = (k2 < 0) ? 4 : ((k2 > 3) ? -4 : 0); k2 += a2; r2f += (float)a2;
    int a3 = (k3 < 0) ? 4 : ((k3 > 3) ? -4 : 0); k3 += a3; r3f += (float)a3;

    float dl0 = (e0 - r0f) * 0.25f;
    float dl1 = (e1 - r1f) * 0.25f;
    float dl2 = (e2 - r2f) * 0.25f;
    float dl3 = (e3 - r3f) * 0.25f;

    float q0 = (k0 == 3) ? dl0 : ((k1 == 3) ? dl1 : ((k2 == 3) ? dl2 : dl3));
    float q1 = (k0 == 2) ? dl0 : ((k1 == 2) ? dl1 : ((k2 == 2) ? dl2 : dl3));
    float q2 = (k0 == 1) ? dl0 : ((k1 == 1) ? dl1 : ((k2 == 1) ? dl2 : dl3));
    float q3 = (k0 == 0) ? dl0 : ((k1 == 0) ? dl1 : ((k2 == 0) ? dl2 : dl3));
    wg0 = q0 + (1.0f - q3);
    wg1 = q1 - q0;
    wg2 = q2 - q1;
    wg3 = q3 - q2;

    int i0 = (int)r0f, i1 = (int)r1f, i2 = (int)r2f;
    const unsigned P1 = 2654435761u, P2 = 805459861u;
    hA = ((unsigned)i0 ^ ((unsigned)i1 * P1) ^ ((unsigned)i2 * P2)) & (CAPM - 1);
    int b0 = i0 + 1 - ((k0 > 2) ? 4 : 0);
    int b1v = i1 + 1 - ((k1 > 2) ? 4 : 0);
    int b2v = i2 + 1 - ((k2 > 2) ? 4 : 0);
    hB = ((unsigned)b0 ^ ((unsigned)b1v * P1) ^ ((unsigned)b2v * P2)) & (CAPM - 1);
    int c0i = i0 + 2 - ((k0 > 1) ? 4 : 0);
    int c1i = i1 + 2 - ((k1 > 1) ? 4 : 0);
    int c2i = i2 + 2 - ((k2 > 1) ? 4 : 0);
    hC = ((unsigned)c0i ^ ((unsigned)c1i * P1) ^ ((unsigned)c2i * P2)) & (CAPM - 1);
    int e0i = i0 + 3 - ((k0 > 0) ? 4 : 0);
    int e1i = i1 + 3 - ((k1 > 0) ? 4 : 0);
    int e2i = i2 + 3 - ((k2 > 0) ? 4 : 0);
    hD = ((unsigned)e0i ^ ((unsigned)e1i * P1) ^ ((unsigned)e2i * P2)) & (CAPM - 1);
}

__global__ __launch_bounds__(256)
void sdf_fused(const float* __restrict__ points,
               const float* __restrict__ tables,
               const float* __restrict__ shifts,
               const float* __restrict__ w1, const float* __restrict__ b1,
               const float* __restrict__ w2, const float* __restrict__ b2,
               const float* __restrict__ w3, const float* __restrict__ b3,
               const float* __restrict__ w4, const float* __restrict__ b4,
               const float* __restrict__ cons,
               float* __restrict__ out, int N)
{
    int pid = blockIdx.x * blockDim.x + threadIdx.x;
    if (pid >= N) return;

    float px = points[3 * pid + 0];
    float py = points[3 * pid + 1];
    float pz = points[3 * pid + 2];

    // h1 = b1 + (points*0.001) @ w1[48:51,:]
    float h1[HID];
    float cx = px * 0.001f, cy = py * 0.001f, cz = pz * 0.001f;
    #pragma unroll
    for (int j = 0; j < HID; j++) {
        float v = b1[j];
        v = fmaf(cx, w1[48 * HID + j], v);
        v = fmaf(cy, w1[49 * HID + j], v);
        v = fmaf(cz, w1[50 * HID + j], v);
        h1[j] = v;
    }

    int La = (int)cons[2 * NLEV];   // active levels form a prefix (win>0 iff l<alpha)

    // Software-pipelined level loop (depth 2): gathers for level l are issued
    // one iteration before consumption, covered by next level's lattice setup
    // and the previous level's 64 h1-FMAs.
    float wg0, wg1, wg2, wg3, win;
    unsigned hA, hB, hC, hD;
    level_setup(px, py, pz, shifts, cons, 0, wg0, wg1, wg2, wg3, win, hA, hB, hC, hD);
    const float2* tab0 = (const float2*)tables;
    float2 gA = tab0[hA], gB = tab0[hB], gC = tab0[hC], gD = tab0[hD];

    for (int l = 1; l < La; ++l) {
        float nw0, nw1, nw2, nw3, nwin;
        unsigned nA, nB, nC, nD;
        level_setup(px, py, pz, shifts, cons, l, nw0, nw1, nw2, nw3, nwin, nA, nB, nC, nD);
        const float2* tab = (const float2*)tables + (size_t)l * CAPM;
        float2 pgA = tab[nA], pgB = tab[nB], pgC = tab[nC], pgD = tab[nD];

        // consume level l-1
        float f0 = (wg0 * gA.x + wg1 * gB.x + wg2 * gC.x + wg3 * gD.x) * win;
        float f1 = (wg0 * gA.y + wg1 * gB.y + wg2 * gC.y + wg3 * gD.y) * win;
        const float* wr0 = w1 + (2 * (l - 1)) * HID;
        const float* wr1 = wr0 + HID;
        #pragma unroll
        for (int j = 0; j < HID; j++)
            h1[j] = fmaf(f1, wr1[j], fmaf(f0, wr0[j], h1[j]));

        wg0 = nw0; wg1 = nw1; wg2 = nw2; wg3 = nw3; win = nwin;
        gA = pgA; gB = pgB; gC = pgC; gD = pgD;
    }
    {   // epilogue: consume level La-1
        float f0 = (wg0 * gA.x + wg1 * gB.x + wg2 * gC.x + wg3 * gD.x) * win;
        float f1 = (wg0 * gA.y + wg1 * gB.y + wg2 * gC.y + wg3 * gD.y) * win;
        const float* wr0 = w1 + (2 * (La - 1)) * HID;
        const float* wr1 = wr0 + HID;
        #pragma unroll
        for (int j = 0; j < HID; j++)
            h1[j] = fmaf(f1, wr1[j], fmaf(f0, wr0[j], h1[j]));
    }

    // layer 2
    float g[HID];
    #pragma unroll
    for (int i = 0; i < HID; i++) g[i] = gelu_fast(h1[i]);
    float h2[HID];
    #pragma unroll
    for (int j = 0; j < HID; j++) h2[j] = b2[j];
    #pragma unroll
    for (int i = 0; i < HID; i++) {
        float gi = g[i];
        #pragma unroll
        for (int j = 0; j < HID; j++) h2[j] = fmaf(gi, w2[i * HID + j], h2[j]);
    }
    // layer 3 (reuse h1)
    #pragma unroll
    for (int i = 0; i < HID; i++) g[i] = gelu_fast(h2[i]);
    #pragma unroll
    for (int j = 0; j < HID; j++) h1[j] = b3[j];
    #pragma unroll
    for (int i = 0; i < HID; i++) {
        float gi = g[i];
        #pragma unroll
        for (int j = 0; j < HID; j++) h1[j] = fmaf(gi, w3[i * HID + j], h1[j]);
    }
    // layer 4: 33 outputs
    #pragma unroll
    for (int i = 0; i < HID; i++) g[i] = gelu_fast(h1[i]);
    float o[33];
    #pragma unroll
    for (int j = 0; j < 33; j++) o[j] = b4[j];
    #pragma unroll
    for (int i = 0; i < HID; i++) {
        float gi = g[i];
        #pragma unroll
        for (int j = 0; j < 33; j++) o[j] = fmaf(gi, w4[i * 33 + j], o[j]);
    }

    out[pid] = o[0];                              // sdf
    float* geo = out + N + (size_t)pid * 32;      // geom_feat
    #pragma unroll
    for (int j = 0; j < 32; j += 4) {
        float4 v = make_float4(o[1 + j], o[2 + j], o[3 + j], o[4 + j]);
        *reinterpret_cast<float4*>(geo + j) = v;
    }
}

extern "C" void kernel_launch(void* const* d_in, const int* in_sizes, int n_in,
                              void* d_out, int out_size, void* d_ws, size_t ws_size,
                              hipStream_t stream) {
    const float* points = (const float*)d_in[0];
    const int*   iter_p = (const int*)d_in[1];
    const float* tables = (const float*)d_in[2];
    const float* shifts = (const float*)d_in[3];
    const float* w1 = (const float*)d_in[4];
    const float* b1 = (const float*)d_in[5];
    const float* w2 = (const float*)d_in[6];
    const float* b2 = (const float*)d_in[7];
    const float* w3 = (const float*)d_in[8];
    const float* b3 = (const float*)d_in[9];
    const float* w4 = (const float*)d_in[10];
    const float* b4 = (const float*)d_in[11];
    float* out = (float*)d_out;
    float* ws  = (float*)d_ws;
    int N = in_sizes[0] / 3;

    init_consts<<<1, 64, 0, stream>>>(iter_p, ws);
    int block = 256;
    int grid = (N + block - 1) / block;
    sdf_fused<<<grid, block, 0, stream>>>(points, tables, shifts,
                                          w1, b1, w2, b2, w3, b3, w4, b4,
                                          ws, out, N);
}

// Round 3
// 445.813 us; speedup vs baseline: 3.0205x; 3.0205x over previous
//
#include <hip/hip_runtime.h>
#include <math.h>

#define NLEV 24
#define CAPM 262144
#define HID 32
#define CHUNK 4

// ws layout: [0..23] = 1/scale (fp32-rounded like reference), [24..47] = c2f window,
//            [48] = number of active levels (prefix with window > 0)
__global__ void init_consts(const int* __restrict__ iter_p, float* __restrict__ ws) {
    __shared__ float wloc[NLEV];
    int l = threadIdx.x;
    if (l < NLEV) {
        double scale;
        if (l == 0) scale = 1.0;
        else if (l == NLEV - 1) scale = 0.0001;
        else scale = pow(10.0, -((double)(4 * l)) / 23.0);
        float scale_f = (float)scale;                 // reference casts geomspace to fp32
        ws[l] = (float)(1.0 / (double)scale_f);       // correctly-rounded fp32 reciprocal
        float t = (float)iter_p[0] / 10000.0f;
        t = fminf(fmaxf(t, 0.0f), 1.0f);
        float alpha = (0.3f + 0.7f * t) * 24.0f;
        float x = fminf(fmaxf(alpha - (float)l, 0.0f), 1.0f);
        float win = 0.5f * (1.0f - (float)cos(M_PI * (double)x));
        ws[NLEV + l] = win;
        wloc[l] = win;
    }
    __syncthreads();
    if (l == 0) {
        int cnt = 0;
        for (int i = 0; i < NLEV; i++) cnt += (wloc[i] > 0.0f) ? 1 : 0;
        ws[2 * NLEV] = (float)cnt;
    }
}

__device__ __forceinline__ float gelu_exact(float v) {
    return 0.5f * v * (1.0f + erff(v * 0.70710678118654752f));
}

// Permutohedral lattice setup for one level: 4 hash indices + barycentric
// weights (pre-multiplied by the c2f window). Arithmetic identical to the
// round-1 verified version (win folded in linearly; error ~1e-11).
__device__ __forceinline__ void level_setup(
    float px, float py, float pz,
    const float* __restrict__ shifts, const float* __restrict__ cons, int l,
    float* __restrict__ wgt /*4*/, unsigned* __restrict__ hh /*4*/)
{
    const float SF0 = 2.3094010767585034f;  // 4/sqrt(3)
    const float SF1 = 1.3333333333333333f;  // 4/3
    const float SF2 = 0.9428090415820634f;  // 2*sqrt(2)/3

    float win = cons[NLEV + l];
    float inv = cons[l];
    float p0 = fmaf(px, inv, shifts[3 * l + 0]);
    float p1 = fmaf(py, inv, shifts[3 * l + 1]);
    float p2 = fmaf(pz, inv, shifts[3 * l + 2]);
    float c0 = p0 * SF0, c1 = p1 * SF1, c2 = p2 * SF2;
    float s1 = c1 + c2;
    float s0 = c0 + s1;
    float e0 = s0;
    float e1 = s1 - c0;
    float e2 = c2 - 2.0f * c1;
    float e3 = -3.0f * c2;
    float r0f = rintf(e0 * 0.25f) * 4.0f;
    float r1f = rintf(e1 * 0.25f) * 4.0f;
    float r2f = rintf(e2 * 0.25f) * 4.0f;
    float r3f = rintf(e3 * 0.25f) * 4.0f;
    int sum_ = (int)rintf((r0f + r1f + r2f + r3f) * 0.25f);
    float d0 = e0 - r0f, d1 = e1 - r1f, d2 = e2 - r2f, d3 = e3 - r3f;
    // rank = position in stable descending argsort of diff
    int k0 = (int)(d1 > d0) + (int)(d2 > d0) + (int)(d3 > d0) + sum_;
    int k1 = (int)(d0 > d1) + (int)(d2 > d1) + (int)(d3 > d1)
           + (int)(d0 == d1) + sum_;
    int k2 = (int)(d0 > d2) + (int)(d1 > d2) + (int)(d3 > d2)
           + (int)(d0 == d2) + (int)(d1 == d2) + sum_;
    int k3 = (int)(d0 > d3) + (int)(d1 > d3) + (int)(d2 > d3)
           + (int)(d0 == d3) + (int)(d1 == d3) + (int)(d2 == d3) + sum_;
    int a0 = (k0 < 0) ? 4 : ((k0 > 3) ? -4 : 0); k0 += a0; r0f += (float)a0;
    int a1 = (k1 < 0) ? 4 : ((k1 > 3) ? -4 : 0); k1 += a1; r1f += (float)a1;
    int a2 = (k2 < 0) ? 4 : ((k2 > 3) ? -4 : 0); k2 += a2; r2f += (float)a2;
    int a3 = (k3 < 0) ? 4 : ((k3 > 3) ? -4 : 0); k3 += a3; r3f += (float)a3;

    float dl0 = (e0 - r0f) * 0.25f;
    float dl1 = (e1 - r1f) * 0.25f;
    float dl2 = (e2 - r2f) * 0.25f;
    float dl3 = (e3 - r3f) * 0.25f;

    float q0 = (k0 == 3) ? dl0 : ((k1 == 3) ? dl1 : ((k2 == 3) ? dl2 : dl3));
    float q1 = (k0 == 2) ? dl0 : ((k1 == 2) ? dl1 : ((k2 == 2) ? dl2 : dl3));
    float q2 = (k0 == 1) ? dl0 : ((k1 == 1) ? dl1 : ((k2 == 1) ? dl2 : dl3));
    float q3 = (k0 == 0) ? dl0 : ((k1 == 0) ? dl1 : ((k2 == 0) ? dl2 : dl3));
    wgt[0] = (q0 + (1.0f - q3)) * win;
    wgt[1] = (q1 - q0) * win;
    wgt[2] = (q2 - q1) * win;
    wgt[3] = (q3 - q2) * win;

    int i0 = (int)r0f, i1 = (int)r1f, i2 = (int)r2f;
    const unsigned P1 = 2654435761u, P2 = 805459861u;
    hh[0] = ((unsigned)i0 ^ ((unsigned)i1 * P1) ^ ((unsigned)i2 * P2)) & (CAPM - 1);
    int b0 = i0 + 1 - ((k0 > 2) ? 4 : 0);
    int b1v = i1 + 1 - ((k1 > 2) ? 4 : 0);
    int b2v = i2 + 1 - ((k2 > 2) ? 4 : 0);
    hh[1] = ((unsigned)b0 ^ ((unsigned)b1v * P1) ^ ((unsigned)b2v * P2)) & (CAPM - 1);
    int c0i = i0 + 2 - ((k0 > 1) ? 4 : 0);
    int c1i = i1 + 2 - ((k1 > 1) ? 4 : 0);
    int c2i = i2 + 2 - ((k2 > 1) ? 4 : 0);
    hh[2] = ((unsigned)c0i ^ ((unsigned)c1i * P1) ^ ((unsigned)c2i * P2)) & (CAPM - 1);
    int e0i = i0 + 3 - ((k0 > 0) ? 4 : 0);
    int e1i = i1 + 3 - ((k1 > 0) ? 4 : 0);
    int e2i = i2 + 3 - ((k2 > 0) ? 4 : 0);
    hh[3] = ((unsigned)e0i ^ ((unsigned)e1i * P1) ^ ((unsigned)e2i * P2)) & (CAPM - 1);
}

__global__ __launch_bounds__(256)
void sdf_fused(const float* __restrict__ points,
               const float* __restrict__ tables,
               const float* __restrict__ shifts,
               const float* __restrict__ w1, const float* __restrict__ b1,
               const float* __restrict__ w2, const float* __restrict__ b2,
               const float* __restrict__ w3, const float* __restrict__ b3,
               const float* __restrict__ w4, const float* __restrict__ b4,
               const float* __restrict__ cons,
               float* __restrict__ out, int N)
{
    int pid = blockIdx.x * blockDim.x + threadIdx.x;
    if (pid >= N) return;

    float px = points[3 * pid + 0];
    float py = points[3 * pid + 1];
    float pz = points[3 * pid + 2];

    // h1 = b1 + (points*0.001) @ w1[48:51,:]
    float h1[HID];
    float cx = px * 0.001f, cy = py * 0.001f, cz = pz * 0.001f;
    #pragma unroll
    for (int j = 0; j < HID; j++) {
        float v = b1[j];
        v = fmaf(cx, w1[48 * HID + j], v);
        v = fmaf(cy, w1[49 * HID + j], v);
        v = fmaf(cz, w1[50 * HID + j], v);
        h1[j] = v;
    }

    int La = (int)cons[2 * NLEV];    // active levels = prefix (always >= 8)
    int Lc = La & ~(CHUNK - 1);      // chunked portion

    // Chunk-of-4, double-buffered gather pipeline: 16-32 loads in flight.
    if (Lc >= CHUNK) {
        float  wA[4 * CHUNK];
        float2 rA[4 * CHUNK];
        #pragma unroll
        for (int t = 0; t < CHUNK; t++) {
            unsigned hh[4];
            level_setup(px, py, pz, shifts, cons, t, &wA[4 * t], hh);
            const float2* tab = (const float2*)tables + (size_t)t * CAPM;
            rA[4 * t + 0] = tab[hh[0]];
            rA[4 * t + 1] = tab[hh[1]];
            rA[4 * t + 2] = tab[hh[2]];
            rA[4 * t + 3] = tab[hh[3]];
        }
        int lprev = 0;
        for (int base = CHUNK; base < Lc; base += CHUNK) {
            float  wB[4 * CHUNK];
            float2 rB[4 * CHUNK];
            #pragma unroll
            for (int t = 0; t < CHUNK; t++) {
                unsigned hh[4];
                level_setup(px, py, pz, shifts, cons, base + t, &wB[4 * t], hh);
                const float2* tab = (const float2*)tables + (size_t)(base + t) * CAPM;
                rB[4 * t + 0] = tab[hh[0]];
                rB[4 * t + 1] = tab[hh[1]];
                rB[4 * t + 2] = tab[hh[2]];
                rB[4 * t + 3] = tab[hh[3]];
            }
            // consume previous chunk while this chunk's loads are in flight
            #pragma unroll
            for (int t = 0; t < CHUNK; t++) {
                float f0 = wA[4*t+0] * rA[4*t+0].x + wA[4*t+1] * rA[4*t+1].x
                         + wA[4*t+2] * rA[4*t+2].x + wA[4*t+3] * rA[4*t+3].x;
                float f1 = wA[4*t+0] * rA[4*t+0].y + wA[4*t+1] * rA[4*t+1].y
                         + wA[4*t+2] * rA[4*t+2].y + wA[4*t+3] * rA[4*t+3].y;
                const float* wr0 = w1 + (size_t)(2 * (lprev + t)) * HID;
                const float* wr1 = wr0 + HID;
                #pragma unroll
                for (int j = 0; j < HID; j++)
                    h1[j] = fmaf(f1, wr1[j], fmaf(f0, wr0[j], h1[j]));
            }
            #pragma unroll
            for (int i = 0; i < 4 * CHUNK; i++) { wA[i] = wB[i]; rA[i] = rB[i]; }
            lprev = base;
        }
        // epilogue: consume the last chunk
        #pragma unroll
        for (int t = 0; t < CHUNK; t++) {
            float f0 = wA[4*t+0] * rA[4*t+0].x + wA[4*t+1] * rA[4*t+1].x
                     + wA[4*t+2] * rA[4*t+2].x + wA[4*t+3] * rA[4*t+3].x;
            float f1 = wA[4*t+0] * rA[4*t+0].y + wA[4*t+1] * rA[4*t+1].y
                     + wA[4*t+2] * rA[4*t+2].y + wA[4*t+3] * rA[4*t+3].y;
            const float* wr0 = w1 + (size_t)(2 * (lprev + t)) * HID;
            const float* wr1 = wr0 + HID;
            #pragma unroll
            for (int j = 0; j < HID; j++)
                h1[j] = fmaf(f1, wr1[j], fmaf(f0, wr0[j], h1[j]));
        }
    }
    // tail levels (La % 4): rare, latency exposed but only <=3 levels
    for (int l = Lc; l < La; ++l) {
        float wgt[4]; unsigned hh[4];
        level_setup(px, py, pz, shifts, cons, l, wgt, hh);
        const float2* tab = (const float2*)tables + (size_t)l * CAPM;
        float2 g0 = tab[hh[0]], g1 = tab[hh[1]], g2 = tab[hh[2]], g3 = tab[hh[3]];
        float f0 = wgt[0] * g0.x + wgt[1] * g1.x + wgt[2] * g2.x + wgt[3] * g3.x;
        float f1 = wgt[0] * g0.y + wgt[1] * g1.y + wgt[2] * g2.y + wgt[3] * g3.y;
        const float* wr0 = w1 + (size_t)(2 * l) * HID;
        const float* wr1 = wr0 + HID;
        #pragma unroll
        for (int j = 0; j < HID; j++)
            h1[j] = fmaf(f1, wr1[j], fmaf(f0, wr0[j], h1[j]));
    }

    // layer 2
    float g[HID];
    #pragma unroll
    for (int i = 0; i < HID; i++) g[i] = gelu_exact(h1[i]);
    float h2[HID];
    #pragma unroll
    for (int j = 0; j < HID; j++) h2[j] = b2[j];
    #pragma unroll
    for (int i = 0; i < HID; i++) {
        float gi = g[i];
        #pragma unroll
        for (int j = 0; j < HID; j++) h2[j] = fmaf(gi, w2[i * HID + j], h2[j]);
    }
    // layer 3 (reuse h1)
    #pragma unroll
    for (int i = 0; i < HID; i++) g[i] = gelu_exact(h2[i]);
    #pragma unroll
    for (int j = 0; j < HID; j++) h1[j] = b3[j];
    #pragma unroll
    for (int i = 0; i < HID; i++) {
        float gi = g[i];
        #pragma unroll
        for (int j = 0; j < HID; j++) h1[j] = fmaf(gi, w3[i * HID + j], h1[j]);
    }
    // layer 4: 33 outputs
    #pragma unroll
    for (int i = 0; i < HID; i++) g[i] = gelu_exact(h1[i]);
    float o[33];
    #pragma unroll
    for (int j = 0; j < 33; j++) o[j] = b4[j];
    #pragma unroll
    for (int i = 0; i < HID; i++) {
        float gi = g[i];
        #pragma unroll
        for (int j = 0; j < 33; j++) o[j] = fmaf(gi, w4[i * 33 + j], o[j]);
    }

    out[pid] = o[0];                              // sdf
    float* geo = out + N + (size_t)pid * 32;      // geom_feat
    #pragma unroll
    for (int j = 0; j < 32; j += 4) {
        float4 v = make_float4(o[1 + j], o[2 + j], o[3 + j], o[4 + j]);
        *reinterpret_cast<float4*>(geo + j) = v;
    }
}

extern "C" void kernel_launch(void* const* d_in, const int* in_sizes, int n_in,
                              void* d_out, int out_size, void* d_ws, size_t ws_size,
                              hipStream_t stream) {
    const float* points = (const float*)d_in[0];
    const int*   iter_p = (const int*)d_in[1];
    const float* tables = (const float*)d_in[2];
    const float* shifts = (const float*)d_in[3];
    const float* w1 = (const float*)d_in[4];
    const float* b1 = (const float*)d_in[5];
    const float* w2 = (const float*)d_in[6];
    const float* b2 = (const float*)d_in[7];
    const float* w3 = (const float*)d_in[8];
    const float* b3 = (const float*)d_in[9];
    const float* w4 = (const float*)d_in[10];
    const float* b4 = (const float*)d_in[11];
    float* out = (float*)d_out;
    float* ws  = (float*)d_ws;
    int N = in_sizes[0] / 3;

    init_consts<<<1, 64, 0, stream>>>(iter_p, ws);
    int block = 256;
    int grid = (N + block - 1) / block;
    sdf_fused<<<grid, block, 0, stream>>>(points, tables, shifts,
                                          w1, b1, w2, b2, w3, b3, w4, b4,
                                          ws, out, N);
}